// Round 3
// baseline (14.080 us; speedup 1.0000x reference)
//
#include <hip/hip_runtime.h>
#include <math.h>

#define WID 640
#define HEI 480
#define HW (WID * HEI)
#define SEEDS 8192
#define NBOX 512
#define NFEAT 18
#define TPS 32              // threads (lanes) per seed
#define SPB 8               // seeds per block (256 / TPS)

__global__ __launch_bounds__(256) void votefusion_kernel(
    const float* __restrict__ img,     // B,3,H,W
    const float* __restrict__ bb,      // B,N,6  (l,t,r,b,conf,cls)
    const float* __restrict__ seeds,   // B,S,3
    const float* __restrict__ Rt,      // B,3,3
    const float* __restrict__ Km,      // B,3,3
    float* __restrict__ out)           // B,18,S
{
    const int b   = blockIdx.y;
    const int tid = threadIdx.x;
    const int grp = tid >> 5;           // seed slot in block
    const int t   = tid & 31;           // lane within seed group
    const int s   = blockIdx.x * SPB + grp;

    __shared__ float2 s_lr[NBOX];       // (l, r)
    __shared__ float2 s_tb[NBOX];       // (t, b)

    const float* bbB = bb + (size_t)b * NBOX * 6;
    #pragma unroll
    for (int j = tid; j < NBOX; j += 256) {
        const float2 lt = *(const float2*)(bbB + j * 6);      // (l, t)
        const float2 rb = *(const float2*)(bbB + j * 6 + 2);  // (r, b)
        s_lr[j] = make_float2(lt.x, rb.x);
        s_tb[j] = make_float2(lt.y, rb.y);
    }
    __syncthreads();

    // Per-sample matrices (uniform per batch)
    const float* R  = Rt + (size_t)b * 9;
    const float* Ko = Km + (size_t)b * 9;
    const float R00 = R[0], R01 = R[1], R02 = R[2];
    const float R10 = R[3], R11 = R[4], R12 = R[5];
    const float R20 = R[6], R21 = R[7], R22 = R[8];
    const float K00 = Ko[0], K01 = Ko[1], K02 = Ko[2];
    const float K10 = Ko[3], K11 = Ko[4], K12 = Ko[5];
    const float K20 = Ko[6], K21 = Ko[7], K22 = Ko[8];

    // Seed -> cam -> 2D projection (redundant across the 32 lanes of a group)
    const float* sp = seeds + ((size_t)b * SEEDS + s) * 3;
    const float s0 = sp[0], s1 = sp[1], s2 = sp[2];
    const float q0 = R00 * s0 + R01 * s1 + R02 * s2;
    const float q1 = R10 * s0 + R11 * s1 + R12 * s2;
    const float q2 = R20 * s0 + R21 * s1 + R22 * s2;
    const float cam0 = q0, cam1 = -q2, cam2 = q1;
    const float uv0 = K00 * cam0 + K01 * cam1 + K02 * cam2;
    const float uv1 = K10 * cam0 + K11 * cam1 + K12 * cam2;
    const float uv2 = K20 * cam0 + K21 * cam1 + K22 * cam2;
    const float sxe = uv0 / uv2;
    const float sye = uv1 / uv2;

    // Scan my 16 boxes (interleaved): packed argmin key + any-in-box
    unsigned long long key = 0xFFFFFFFFFFFFFFFFull;
    int any = 0;
    #pragma unroll 4
    for (int i = 0; i < NBOX / TPS; ++i) {
        const int j = i * TPS + t;
        const float2 lr = s_lr[j];
        const float2 tb = s_tb[j];
        // midx/midy with the same rounding sequence as the reference
        const float midx = __fmul_rn(__fadd_rn(lr.x, lr.y), 0.5f);
        const float midy = __fmul_rn(__fadd_rn(tb.x, tb.y), 0.5f);
        const float du = __fsub_rn(midx, sxe);
        const float dv = __fsub_rn(midy, sye);
        const float d2 = __fadd_rn(__fmul_rn(du, du), __fmul_rn(dv, dv));
        const unsigned long long k =
            ((unsigned long long)__float_as_uint(d2) << 32) | (unsigned)j;
        key = (k < key) ? k : key;
        any |= (sxe > lr.x) & (sxe < lr.y) & (sye > tb.x) & (sye < tb.y);
    }

    // Butterfly min-reduce of the packed key across the 32-lane group
    #pragma unroll
    for (int m = 1; m < TPS; m <<= 1) {
        const unsigned long long ok = __shfl_xor(key, m);
        key = (ok < key) ? ok : key;
    }
    // any-reduce via ballot (per 32-lane half)
    {
        const unsigned long long bal = __ballot(any != 0);
        any = ((unsigned)(bal >> (tid & 32)) != 0u);
    }

    const int bi = (int)(unsigned)(key & 0xFFFFFFFFull);

    // Parallel epilogue: lane t produces feature t (t < 18)
    float val = 0.0f;
    if (any && t < NFEAT) {
        if (t < 10) {
            // sem one-hot * conf at assigned box (broadcast loads)
            const float conf = bbB[bi * 6 + 4];
            const int   cls  = (int)bbB[bi * 6 + 5];
            val = (t == cls) ? conf : 0.0f;
        } else if (t < 13) {
            // txt: gather image at clipped/floored seed 2D position
            const float sx = fminf(fmaxf(sxe, 0.0f), (float)(WID - 1));
            const float sy = fminf(fmaxf(sye, 0.0f), (float)(HEI - 1));
            const int ix = (int)floorf(sx);
            const int iy = (int)floorf(sy);
            const int pidx = iy * WID + ix;
            const float mc = (t == 10) ? 103.53f : (t == 11) ? 116.28f : 123.675f;
            const float* imgB = img + (size_t)b * 3 * HW;
            val = ((imgB[(t - 10) * HW + pidx] + mc) - 128.0f) * (1.0f / 128.0f);
        } else {
            // geo cue at assigned box (5 lanes, redundant math)
            const float2 lr = s_lr[bi];
            const float2 tb = s_tb[bi];
            const float midx = __fmul_rn(__fadd_rn(lr.x, lr.y), 0.5f);
            const float midy = __fmul_rn(__fadd_rn(tb.x, tb.y), 0.5f);
            const float du = midx - sxe;
            const float dv = midy - sye;
            const float x3 = cam0, y3 = cam1, z3 = cam2;
            const float geo0 = du * (z3 / K00);
            const float geo1 = dv * (z3 / K11);

            // geo_xy = (geo0, 0, -geo1) @ Rt
            const float gxy0 = geo0 * R00 - geo1 * R20;
            const float gxy1 = geo0 * R01 - geo1 * R21;
            const float gxy2 = geo0 * R02 - geo1 * R22;
            const float ratio = s1 / (s1 + gxy1);
            const float gx = gxy0 * ratio;
            const float gz = gxy2 * ratio;

            // geo_vec = (geo0+x3, z3, -(geo1+y3)) @ Rt, normalized
            const float a0 = geo0 + x3;
            const float a1 = z3;
            const float a2 = -(geo1 + y3);
            const float gv0 = a0 * R00 + a1 * R10 + a2 * R20;
            const float gv1 = a0 * R01 + a1 * R11 + a2 * R21;
            const float gv2 = a0 * R02 + a1 * R12 + a2 * R22;
            const float inr = 1.0f / sqrtf(gv0 * gv0 + gv1 * gv1 + gv2 * gv2);
            val = (t == 13) ? gx
                : (t == 14) ? gz
                : (t == 15) ? gv0 * inr
                : (t == 16) ? gv1 * inr
                :             gv2 * inr;
        }
    }

    if (t < NFEAT) {
        const size_t base = (size_t)b * NFEAT * SEEDS + s;
        out[base + (size_t)t * SEEDS] = val;
    }
}

extern "C" void kernel_launch(void* const* d_in, const int* in_sizes, int n_in,
                              void* d_out, int out_size, void* d_ws, size_t ws_size,
                              hipStream_t stream) {
    const float* img   = (const float*)d_in[0];
    const float* bb    = (const float*)d_in[1];
    const float* seeds = (const float*)d_in[2];
    const float* Rt    = (const float*)d_in[3];
    const float* K     = (const float*)d_in[4];
    float* out = (float*)d_out;

    const int B = in_sizes[1] / (NBOX * 6);
    dim3 grid(SEEDS / SPB, B);
    votefusion_kernel<<<grid, 256, 0, stream>>>(img, bb, seeds, Rt, K, out);
}

// Round 5
// 13.231 us; speedup vs baseline: 1.0642x; 1.0642x over previous
//
#include <hip/hip_runtime.h>
#include <math.h>

#define WID 640
#define HEI 480
#define HW (WID * HEI)
#define SEEDS 8192
#define NBOX 512
#define NFEAT 18
#define TPS 32              // threads (lanes) per seed
#define SPB 8               // seeds per block (256 / TPS)

__global__ __launch_bounds__(256) void votefusion_kernel(
    const float* __restrict__ img,     // B,3,H,W
    const float* __restrict__ bb,      // B,N,6  (l,t,r,b,conf,cls)
    const float* __restrict__ seeds,   // B,S,3
    const float* __restrict__ Rt,      // B,3,3
    const float* __restrict__ Km,      // B,3,3
    float* __restrict__ out)           // B,18,S
{
    const int b   = blockIdx.y;
    const int tid = threadIdx.x;
    const int grp = tid >> 5;           // seed slot in block
    const int t   = tid & 31;           // lane within seed group
    const int s   = blockIdx.x * SPB + grp;

    const float* bbB = bb + (size_t)b * NBOX * 6;

    // Per-sample matrices (uniform per batch -> scalar loads)
    const float* R  = Rt + (size_t)b * 9;
    const float* Ko = Km + (size_t)b * 9;
    const float R00 = R[0], R01 = R[1], R02 = R[2];
    const float R10 = R[3], R11 = R[4], R12 = R[5];
    const float R20 = R[6], R21 = R[7], R22 = R[8];
    const float K00 = Ko[0], K01 = Ko[1], K02 = Ko[2];
    const float K10 = Ko[3], K11 = Ko[4], K12 = Ko[5];
    const float K20 = Ko[6], K21 = Ko[7], K22 = Ko[8];

    // Seed -> cam -> 2D projection (redundant across the 32 lanes of a group)
    const float* sp = seeds + ((size_t)b * SEEDS + s) * 3;
    const float s0 = sp[0], s1 = sp[1], s2 = sp[2];
    const float q0 = R00 * s0 + R01 * s1 + R02 * s2;
    const float q1 = R10 * s0 + R11 * s1 + R12 * s2;
    const float q2 = R20 * s0 + R21 * s1 + R22 * s2;
    const float cam0 = q0, cam1 = -q2, cam2 = q1;
    const float uv0 = K00 * cam0 + K01 * cam1 + K02 * cam2;
    const float uv1 = K10 * cam0 + K11 * cam1 + K12 * cam2;
    const float uv2 = K20 * cam0 + K21 * cam1 + K22 * cam2;
    const float sxe = uv0 / uv2;
    const float sye = uv1 / uv2;

    // Scan my 16 boxes (interleaved, straight from global/L1):
    // packed argmin key + any-in-box
    unsigned long long key = 0xFFFFFFFFFFFFFFFFull;
    int any = 0;
    #pragma unroll
    for (int i = 0; i < NBOX / TPS; ++i) {
        const int j = i * TPS + t;
        const float2 lt = *(const float2*)(bbB + j * 6);      // (l, t)
        const float2 rb = *(const float2*)(bbB + j * 6 + 2);  // (r, b)
        // midx/midy with the same rounding sequence as the reference
        const float midx = __fmul_rn(__fadd_rn(lt.x, rb.x), 0.5f);
        const float midy = __fmul_rn(__fadd_rn(lt.y, rb.y), 0.5f);
        const float du = __fsub_rn(midx, sxe);
        const float dv = __fsub_rn(midy, sye);
        const float d2 = __fadd_rn(__fmul_rn(du, du), __fmul_rn(dv, dv));
        const unsigned long long k =
            ((unsigned long long)__float_as_uint(d2) << 32) | (unsigned)j;
        key = (k < key) ? k : key;
        any |= (sxe > lt.x) & (sxe < rb.x) & (sye > lt.y) & (sye < rb.y);
    }

    // Butterfly min-reduce of the packed key across the 32-lane group
    #pragma unroll
    for (int m = 1; m < TPS; m <<= 1) {
        const unsigned long long ok = __shfl_xor(key, m);
        key = (ok < key) ? ok : key;
    }
    // any-reduce via ballot (per 32-lane half)
    {
        const unsigned long long bal = __ballot(any != 0);
        any = ((unsigned)(bal >> (tid & 32)) != 0u);
    }

    const int bi = (int)(unsigned)(key & 0xFFFFFFFFull);

    // Parallel epilogue: lane t produces feature t (t < 18)
    float val = 0.0f;
    if (any && t < NFEAT) {
        if (t < 10) {
            // sem one-hot * conf at assigned box (broadcast loads)
            const float conf = bbB[bi * 6 + 4];
            const int   cls  = (int)bbB[bi * 6 + 5];
            val = (t == cls) ? conf : 0.0f;
        } else if (t < 13) {
            // txt: gather image at clipped/floored seed 2D position
            const float sx = fminf(fmaxf(sxe, 0.0f), (float)(WID - 1));
            const float sy = fminf(fmaxf(sye, 0.0f), (float)(HEI - 1));
            const int ix = (int)floorf(sx);
            const int iy = (int)floorf(sy);
            const int pidx = iy * WID + ix;
            const float mc = (t == 10) ? 103.53f : (t == 11) ? 116.28f : 123.675f;
            const float* imgB = img + (size_t)b * 3 * HW;
            val = ((imgB[(t - 10) * HW + pidx] + mc) - 128.0f) * (1.0f / 128.0f);
        } else {
            // geo cue at assigned box (5 lanes, redundant math)
            const float2 lt = *(const float2*)(bbB + bi * 6);
            const float2 rb = *(const float2*)(bbB + bi * 6 + 2);
            const float midx = __fmul_rn(__fadd_rn(lt.x, rb.x), 0.5f);
            const float midy = __fmul_rn(__fadd_rn(lt.y, rb.y), 0.5f);
            const float du = midx - sxe;
            const float dv = midy - sye;
            const float x3 = cam0, y3 = cam1, z3 = cam2;
            const float geo0 = du * (z3 / K00);
            const float geo1 = dv * (z3 / K11);

            // geo_xy = (geo0, 0, -geo1) @ Rt
            const float gxy0 = geo0 * R00 - geo1 * R20;
            const float gxy1 = geo0 * R01 - geo1 * R21;
            const float gxy2 = geo0 * R02 - geo1 * R22;
            const float ratio = s1 / (s1 + gxy1);
            const float gx = gxy0 * ratio;
            const float gz = gxy2 * ratio;

            // geo_vec = (geo0+x3, z3, -(geo1+y3)) @ Rt, normalized
            const float a0 = geo0 + x3;
            const float a1 = z3;
            const float a2 = -(geo1 + y3);
            const float gv0 = a0 * R00 + a1 * R10 + a2 * R20;
            const float gv1 = a0 * R01 + a1 * R11 + a2 * R21;
            const float gv2 = a0 * R02 + a1 * R12 + a2 * R22;
            const float inr = 1.0f / sqrtf(gv0 * gv0 + gv1 * gv1 + gv2 * gv2);
            val = (t == 13) ? gx
                : (t == 14) ? gz
                : (t == 15) ? gv0 * inr
                : (t == 16) ? gv1 * inr
                :             gv2 * inr;
        }
    }

    if (t < NFEAT) {
        const size_t base = (size_t)b * NFEAT * SEEDS + s;
        out[base + (size_t)t * SEEDS] = val;
    }
}

extern "C" void kernel_launch(void* const* d_in, const int* in_sizes, int n_in,
                              void* d_out, int out_size, void* d_ws, size_t ws_size,
                              hipStream_t stream) {
    const float* img   = (const float*)d_in[0];
    const float* bb    = (const float*)d_in[1];
    const float* seeds = (const float*)d_in[2];
    const float* Rt    = (const float*)d_in[3];
    const float* K     = (const float*)d_in[4];
    float* out = (float*)d_out;

    const int B = in_sizes[1] / (NBOX * 6);
    dim3 grid(SEEDS / SPB, B);
    votefusion_kernel<<<grid, 256, 0, stream>>>(img, bb, seeds, Rt, K, out);
}